// Round 3
// baseline (2843.530 us; speedup 1.0000x reference)
//
#include <hip/hip_runtime.h>
#include <math.h>

#define S_TOT 2048
#define B_    64
#define E_    256
#define H_    256

// Fused kernel: blocks [0, scan_blocks) run the sequential scan (one block per
// batch); blocks [scan_blocks, grid) run the xp GEMM for the NEXT chunk.
// Kernel-boundary acts as the producer->consumer sync between chunks.
__global__ __launch_bounds__(256, 1) void fused_step(
    const float* __restrict__ A,       // sentence chunk for gemm [Mc, E] (or null)
    const float* __restrict__ Wih,     // [E, H]
    const float* __restrict__ bias,    // [H]
    float*       __restrict__ xp_next, // [chunk*B, H] gemm output
    const float* __restrict__ xp_cur,  // [steps, B, H] scan input (or null)
    const float* __restrict__ Whh,     // [H, H]
    float*       __restrict__ h,       // [B, H] persistent state (= d_out)
    int steps, int scan_blocks)
{
    __shared__ float smem[32 * 68 + 32 * 64];   // gemm tiles; scan reuses front
    const int tid = threadIdx.x;

    if ((int)blockIdx.x < scan_blocks) {
        // ---------------- scan: h_new = tanh(xp + h @ Whh) ----------------
        // thread (jg = tid>>3, ks = tid&7): outputs j0..j0+7, k in [ks*32, ks*32+32)
        float* hbuf = smem;              // [2][8 segs][32 + 4 pad] = 2*288 floats
        const int b  = blockIdx.x;
        const int ks = tid & 7;
        const int jg = tid >> 3;
        const int j0 = jg << 3;
        // output index this lane holds after the split-butterfly reduction:
        const int jf = j0 + ((ks & 1) << 2) + (ks & 2) + ((ks >> 2) & 1);

        // W slice in registers: w4[k][0]=Whh[ks*32+k][j0..j0+3], [1]=cols j0+4..7
        float4 w4[32][2];
        #pragma unroll
        for (int k = 0; k < 32; k++) {
            const float* wr = &Whh[(size_t)(ks * 32 + k) * H_ + j0];
            w4[k][0] = *(const float4*)wr;
            w4[k][1] = *(const float4*)(wr + 4);
        }

        hbuf[(tid >> 5) * 36 + (tid & 31)] = h[b * H_ + tid];
        float xpn = xp_cur[(size_t)b * H_ + jf];
        __syncthreads();

        int p = 0;
        for (int s = 0; s < steps; s++) {
            const float xpc = xpn;
            if (s + 1 < steps)
                xpn = xp_cur[((size_t)(s + 1) * B_ + b) * H_ + jf];

            // 8 conflict-free multicast reads: addr dw = p*288 + ks*36 + i*4
            const float4* hv = (const float4*)&hbuf[p * 288 + ks * 36];
            float acc[8] = {0.f, 0.f, 0.f, 0.f, 0.f, 0.f, 0.f, 0.f};
            #pragma unroll
            for (int i = 0; i < 8; i++) {
                const float4 h4 = hv[i];
                #pragma unroll
                for (int e = 0; e < 4; e++) {
                    const float hk = (e == 0) ? h4.x : (e == 1) ? h4.y : (e == 2) ? h4.z : h4.w;
                    const float4 wlo = w4[i * 4 + e][0];
                    const float4 whi = w4[i * 4 + e][1];
                    acc[0] += hk * wlo.x; acc[1] += hk * wlo.y;
                    acc[2] += hk * wlo.z; acc[3] += hk * wlo.w;
                    acc[4] += hk * whi.x; acc[5] += hk * whi.y;
                    acc[6] += hk * whi.z; acc[7] += hk * whi.w;
                }
            }

            // split-butterfly reduce across the 8 ks lanes (7 shuffles total);
            // each lane ends with ONE fully-reduced output (index jf).
            const bool b0 = (ks & 1), b1 = (ks & 2), b2 = (ks & 4);
            float r0, r1, r2, r3, q0, q1, v;
            {   // xor 1: even keeps 0..3, odd keeps 4..7
                float s0 = b0 ? acc[0] : acc[4];
                float s1 = b0 ? acc[1] : acc[5];
                float s2 = b0 ? acc[2] : acc[6];
                float s3 = b0 ? acc[3] : acc[7];
                r0 = (b0 ? acc[4] : acc[0]) + __shfl_xor(s0, 1);
                r1 = (b0 ? acc[5] : acc[1]) + __shfl_xor(s1, 1);
                r2 = (b0 ? acc[6] : acc[2]) + __shfl_xor(s2, 1);
                r3 = (b0 ? acc[7] : acc[3]) + __shfl_xor(s3, 1);
            }
            {   // xor 2: bit-clear keeps r0,r1
                float s0 = b1 ? r0 : r2;
                float s1 = b1 ? r1 : r3;
                q0 = (b1 ? r2 : r0) + __shfl_xor(s0, 2);
                q1 = (b1 ? r3 : r1) + __shfl_xor(s1, 2);
            }
            {   // xor 4: bit-clear keeps q0
                float s0 = b2 ? q0 : q1;
                v = (b2 ? q1 : q0) + __shfl_xor(s0, 4);
            }

            v += xpc;
            const float e = __expf(2.f * v);
            const float hn = 1.f - 2.f / (e + 1.f);   // tanh(v)
            hbuf[(p ^ 1) * 288 + (jf >> 5) * 36 + (jf & 31)] = hn;
            __syncthreads();
            p ^= 1;
        }

        h[b * H_ + tid] = hbuf[p * 288 + (tid >> 5) * 36 + (tid & 31)];
    } else if (A != nullptr) {
        // ---------------- gemm: xp_next = A @ Wih + bias ----------------
        float (*As)[68] = (float(*)[68])smem;
        float (*Bs)[64] = (float(*)[64])(smem + 32 * 68);

        const int gid = blockIdx.x - scan_blocks;
        const int bm = (gid >> 2) * 64;
        const int bn = (gid & 3) * 64;
        const int tx = tid & 15;
        const int ty = tid >> 4;

        float acc[4][4] = {};

        const int ar = tid >> 3;
        const int ak = (tid & 7) << 2;
        const int br = tid >> 4;
        const int bc = (tid & 15) << 2;

        for (int k0 = 0; k0 < E_; k0 += 32) {
            float4 a0 = *(const float4*)&A[(size_t)(bm + ar)      * E_ + k0 + ak];
            float4 a1 = *(const float4*)&A[(size_t)(bm + ar + 32) * E_ + k0 + ak];
            float4 bv0 = *(const float4*)&Wih[(size_t)(k0 + br)      * H_ + bn + bc];
            float4 bv1 = *(const float4*)&Wih[(size_t)(k0 + br + 16) * H_ + bn + bc];

            As[ak+0][ar]    = a0.x; As[ak+1][ar]    = a0.y; As[ak+2][ar]    = a0.z; As[ak+3][ar]    = a0.w;
            As[ak+0][ar+32] = a1.x; As[ak+1][ar+32] = a1.y; As[ak+2][ar+32] = a1.z; As[ak+3][ar+32] = a1.w;
            *(float4*)&Bs[br][bc]      = bv0;
            *(float4*)&Bs[br + 16][bc] = bv1;
            __syncthreads();

            #pragma unroll
            for (int kk = 0; kk < 32; kk++) {
                const float4 av = *(const float4*)&As[kk][ty << 2];
                const float4 bv = *(const float4*)&Bs[kk][tx << 2];
                acc[0][0] += av.x*bv.x; acc[0][1] += av.x*bv.y; acc[0][2] += av.x*bv.z; acc[0][3] += av.x*bv.w;
                acc[1][0] += av.y*bv.x; acc[1][1] += av.y*bv.y; acc[1][2] += av.y*bv.z; acc[1][3] += av.y*bv.w;
                acc[2][0] += av.z*bv.x; acc[2][1] += av.z*bv.y; acc[2][2] += av.z*bv.z; acc[2][3] += av.z*bv.w;
                acc[3][0] += av.w*bv.x; acc[3][1] += av.w*bv.y; acc[3][2] += av.w*bv.z; acc[3][3] += av.w*bv.w;
            }
            __syncthreads();
        }

        const float4 bb = *(const float4*)&bias[bn + (tx << 2)];
        #pragma unroll
        for (int i = 0; i < 4; i++) {
            float4 o;
            o.x = acc[i][0] + bb.x;
            o.y = acc[i][1] + bb.y;
            o.z = acc[i][2] + bb.z;
            o.w = acc[i][3] + bb.w;
            *(float4*)&xp_next[(size_t)(bm + (ty << 2) + i) * H_ + bn + (tx << 2)] = o;
        }
    }
}

extern "C" void kernel_launch(void* const* d_in, const int* in_sizes, int n_in,
                              void* d_out, int out_size, void* d_ws, size_t ws_size,
                              hipStream_t stream)
{
    const float* sentence = (const float*)d_in[0];  // [S,B,E]
    const float* h0       = (const float*)d_in[1];  // [B,H]
    const float* W_ih     = (const float*)d_in[2];  // [E,H]
    const float* W_hh     = (const float*)d_in[3];  // [H,H]
    const float* bias     = (const float*)d_in[4];  // [H]
    float* h  = (float*)d_out;
    float* ws = (float*)d_ws;

    // two ping-pong xp buffers, each [chunk*B, H]
    int chunk = 256;
    while ((size_t)2 * chunk * B_ * H_ * sizeof(float) > ws_size && chunk > 32)
        chunk >>= 1;
    const int nchunk = S_TOT / chunk;
    float* buf[2] = { ws, ws + (size_t)chunk * B_ * H_ };

    hipMemcpyAsync(h, h0, B_ * H_ * sizeof(float), hipMemcpyDeviceToDevice, stream);

    // pure gemm for chunk 0
    fused_step<<<chunk * 4, 256, 0, stream>>>(sentence, W_ih, bias, buf[0],
                                              nullptr, W_hh, h, 0, 0);
    for (int c = 0; c < nchunk; c++) {
        const bool last = (c == nchunk - 1);
        const int gemmb = last ? 0 : chunk * 4;
        const float* Anext = last ? nullptr
                                  : sentence + (size_t)(c + 1) * chunk * B_ * E_;
        fused_step<<<64 + gemmb, 256, 0, stream>>>(Anext, W_ih, bias,
                                                   buf[(c + 1) & 1],
                                                   buf[c & 1], W_hh, h,
                                                   chunk, 64);
    }
}

// Round 4
// 1605.102 us; speedup vs baseline: 1.7716x; 1.7716x over previous
//
#include <hip/hip_runtime.h>
#include <math.h>

#define S_TOT 2048
#define B_    64
#define E_    256
#define H_    256

#define KEEP_REG(x) asm volatile("" : "+v"(x))

// Fused kernel: blocks [0, scan_blocks) run the sequential scan (one block per
// batch, 512 threads); blocks [scan_blocks, grid) run the xp GEMM for the NEXT
// chunk (first 256 threads). Kernel boundary = producer->consumer sync.
__global__ __launch_bounds__(512, 2) void fused_step(
    const float* __restrict__ A,       // sentence chunk for gemm [Mc, E] (or null)
    const float* __restrict__ Wih,     // [E, H]
    const float* __restrict__ bias,    // [H]
    float*       __restrict__ xp_next, // [chunk*B, H] gemm output
    const float* __restrict__ xp_cur,  // [steps, B, H] scan input
    const float* __restrict__ Whh,     // [H, H]
    float*       __restrict__ h,       // [B, H] persistent state (= d_out)
    int steps, int scan_blocks)
{
    __shared__ float smem[32 * 68 + 32 * 64];   // gemm tiles; scan reuses front
    const int tid = threadIdx.x;

    if ((int)blockIdx.x < scan_blocks) {
        // ------------- scan: h_new = tanh(xp + h @ Whh), 512 threads ---------
        // thread (jg = tid>>4, ks = tid&15): outputs j0..j0+7 (j0 = jg*8),
        // k-range [ks*16, ks*16+16).  W slice: 16k x 8j = 128 floats in VGPRs
        // (opaque asm barrier defeats the compiler's load-sinking).
        // h ping-pong in LDS: 16 segments of 16 floats, stride 20
        // (ks*20 mod 32 -> <=2-way bank aliasing, free).
        float* hbuf = smem;              // [2][16 seg][20] = 640 floats
        const int b  = blockIdx.x;
        const int ks = tid & 15;
        const int jg = tid >> 4;         // 0..31
        const int j0 = jg << 3;
        // output index this lane holds after the split-butterfly reduction
        const int jf = j0 + ((ks & 1) << 2) + (ks & 2) + ((ks >> 2) & 1);

        float4 w4[16][2];                // [k][lo/hi 4 cols]
        #pragma unroll
        for (int k = 0; k < 16; k++) {
            const float* wr = &Whh[(size_t)(ks * 16 + k) * H_ + j0];
            float4 lo = *(const float4*)wr;
            float4 hi = *(const float4*)(wr + 4);
            KEEP_REG(lo.x); KEEP_REG(lo.y); KEEP_REG(lo.z); KEEP_REG(lo.w);
            KEEP_REG(hi.x); KEEP_REG(hi.y); KEEP_REG(hi.z); KEEP_REG(hi.w);
            w4[k][0] = lo;
            w4[k][1] = hi;
        }

        if (tid < H_) hbuf[(tid >> 4) * 20 + (tid & 15)] = h[b * H_ + tid];
        float xpn = 0.f;
        if (ks < 8) xpn = xp_cur[(size_t)b * H_ + jf];
        __syncthreads();

        int p = 0;
        for (int s = 0; s < steps; s++) {
            const float xpc = xpn;
            if (ks < 8 && s + 1 < steps)
                xpn = xp_cur[((size_t)(s + 1) * B_ + b) * H_ + jf];

            // 4 x ds_read_b128 from this lane's k-segment (multicast across jg)
            const float4* hv = (const float4*)&hbuf[p * 320 + ks * 20];
            float acc[8] = {0.f, 0.f, 0.f, 0.f, 0.f, 0.f, 0.f, 0.f};
            #pragma unroll
            for (int i = 0; i < 4; i++) {
                const float4 h4 = hv[i];
                #pragma unroll
                for (int e = 0; e < 4; e++) {
                    const float hk = (e == 0) ? h4.x : (e == 1) ? h4.y
                                   : (e == 2) ? h4.z : h4.w;
                    const float4 wlo = w4[i * 4 + e][0];
                    const float4 whi = w4[i * 4 + e][1];
                    acc[0] += hk * wlo.x; acc[1] += hk * wlo.y;
                    acc[2] += hk * wlo.z; acc[3] += hk * wlo.w;
                    acc[4] += hk * whi.x; acc[5] += hk * whi.y;
                    acc[6] += hk * whi.z; acc[7] += hk * whi.w;
                }
            }

            // split-butterfly reduce across the 16 ks lanes (8 shuffles);
            // stages xor1/2/4 halve the per-lane set, xor8 is a plain add.
            const bool b0 = (ks & 1), b1 = (ks & 2), b2 = (ks & 4);
            float r0, r1, r2, r3, q0, q1, v;
            {
                float s0 = b0 ? acc[0] : acc[4];
                float s1 = b0 ? acc[1] : acc[5];
                float s2 = b0 ? acc[2] : acc[6];
                float s3 = b0 ? acc[3] : acc[7];
                r0 = (b0 ? acc[4] : acc[0]) + __shfl_xor(s0, 1);
                r1 = (b0 ? acc[5] : acc[1]) + __shfl_xor(s1, 1);
                r2 = (b0 ? acc[6] : acc[2]) + __shfl_xor(s2, 1);
                r3 = (b0 ? acc[7] : acc[3]) + __shfl_xor(s3, 1);
            }
            {
                float s0 = b1 ? r0 : r2;
                float s1 = b1 ? r1 : r3;
                q0 = (b1 ? r2 : r0) + __shfl_xor(s0, 2);
                q1 = (b1 ? r3 : r1) + __shfl_xor(s1, 2);
            }
            {
                float s0 = b2 ? q0 : q1;
                v = (b2 ? q1 : q0) + __shfl_xor(s0, 4);
            }
            v += __shfl_xor(v, 8);       // fold upper/lower 8-lane halves

            v += xpc;
            const float e2 = __expf(2.f * v);
            const float hn = 1.f - 2.f / (e2 + 1.f);   // tanh(v)
            if (ks < 8)
                hbuf[(p ^ 1) * 320 + (jf >> 4) * 20 + (jf & 15)] = hn;
            __syncthreads();
            p ^= 1;
        }

        if (tid < H_) h[b * H_ + tid] = hbuf[p * 320 + (tid >> 4) * 20 + (tid & 15)];
    } else if (A != nullptr && tid < 256) {
        // ---------------- gemm: xp_next = A @ Wih + bias (256 threads) -------
        float (*As)[68] = (float(*)[68])smem;
        float (*Bs)[64] = (float(*)[64])(smem + 32 * 68);

        const int gid = blockIdx.x - scan_blocks;
        const int bm = (gid >> 2) * 64;
        const int bn = (gid & 3) * 64;
        const int tx = tid & 15;
        const int ty = tid >> 4;

        float acc[4][4] = {};

        const int ar = tid >> 3;
        const int ak = (tid & 7) << 2;
        const int br = tid >> 4;
        const int bc = (tid & 15) << 2;

        for (int k0 = 0; k0 < E_; k0 += 32) {
            float4 a0 = *(const float4*)&A[(size_t)(bm + ar)      * E_ + k0 + ak];
            float4 a1 = *(const float4*)&A[(size_t)(bm + ar + 32) * E_ + k0 + ak];
            float4 bv0 = *(const float4*)&Wih[(size_t)(k0 + br)      * H_ + bn + bc];
            float4 bv1 = *(const float4*)&Wih[(size_t)(k0 + br + 16) * H_ + bn + bc];

            As[ak+0][ar]    = a0.x; As[ak+1][ar]    = a0.y; As[ak+2][ar]    = a0.z; As[ak+3][ar]    = a0.w;
            As[ak+0][ar+32] = a1.x; As[ak+1][ar+32] = a1.y; As[ak+2][ar+32] = a1.z; As[ak+3][ar+32] = a1.w;
            *(float4*)&Bs[br][bc]      = bv0;
            *(float4*)&Bs[br + 16][bc] = bv1;
            __syncthreads();

            #pragma unroll
            for (int kk = 0; kk < 32; kk++) {
                const float4 av = *(const float4*)&As[kk][ty << 2];
                const float4 bv = *(const float4*)&Bs[kk][tx << 2];
                acc[0][0] += av.x*bv.x; acc[0][1] += av.x*bv.y; acc[0][2] += av.x*bv.z; acc[0][3] += av.x*bv.w;
                acc[1][0] += av.y*bv.x; acc[1][1] += av.y*bv.y; acc[1][2] += av.y*bv.z; acc[1][3] += av.y*bv.w;
                acc[2][0] += av.z*bv.x; acc[2][1] += av.z*bv.y; acc[2][2] += av.z*bv.z; acc[2][3] += av.z*bv.w;
                acc[3][0] += av.w*bv.x; acc[3][1] += av.w*bv.y; acc[3][2] += av.w*bv.z; acc[3][3] += av.w*bv.w;
            }
            __syncthreads();
        }

        const float4 bb = *(const float4*)&bias[bn + (tx << 2)];
        #pragma unroll
        for (int i = 0; i < 4; i++) {
            float4 o;
            o.x = acc[i][0] + bb.x;
            o.y = acc[i][1] + bb.y;
            o.z = acc[i][2] + bb.z;
            o.w = acc[i][3] + bb.w;
            *(float4*)&xp_next[(size_t)(bm + (ty << 2) + i) * H_ + bn + (tx << 2)] = o;
        }
    }
}

extern "C" void kernel_launch(void* const* d_in, const int* in_sizes, int n_in,
                              void* d_out, int out_size, void* d_ws, size_t ws_size,
                              hipStream_t stream)
{
    const float* sentence = (const float*)d_in[0];  // [S,B,E]
    const float* h0       = (const float*)d_in[1];  // [B,H]
    const float* W_ih     = (const float*)d_in[2];  // [E,H]
    const float* W_hh     = (const float*)d_in[3];  // [H,H]
    const float* bias     = (const float*)d_in[4];  // [H]
    float* h  = (float*)d_out;
    float* ws = (float*)d_ws;

    // two ping-pong xp buffers, each [chunk*B, H]
    int chunk = 256;
    while ((size_t)2 * chunk * B_ * H_ * sizeof(float) > ws_size && chunk > 32)
        chunk >>= 1;
    const int nchunk = S_TOT / chunk;
    float* buf[2] = { ws, ws + (size_t)chunk * B_ * H_ };

    hipMemcpyAsync(h, h0, B_ * H_ * sizeof(float), hipMemcpyDeviceToDevice, stream);

    // pure gemm for chunk 0
    fused_step<<<chunk * 4, 512, 0, stream>>>(sentence, W_ih, bias, buf[0],
                                              nullptr, W_hh, h, 0, 0);
    for (int c = 0; c < nchunk; c++) {
        const bool last = (c == nchunk - 1);
        const int gemmb = last ? 0 : chunk * 4;
        const float* Anext = last ? nullptr
                                  : sentence + (size_t)(c + 1) * chunk * B_ * E_;
        fused_step<<<64 + gemmb, 512, 0, stream>>>(Anext, W_ih, bias,
                                                   buf[(c + 1) & 1],
                                                   buf[c & 1], W_hh, h,
                                                   chunk, 64);
    }
}